// Round 2
// baseline (676.898 us; speedup 1.0000x reference)
//
#include <hip/hip_runtime.h>
#include <hip/hip_bf16.h>

#define NPTS 200000
#define CIN 64
#define COUT 64
#define KVOL 27
#define NPAIRS 100000
#define GROUPS_PER_K (NPAIRS / 16)                                               // 6250
#define GROUPS_PER_BLOCK 64
#define CHUNKS_PER_K ((GROUPS_PER_K + GROUPS_PER_BLOCK - 1) / GROUPS_PER_BLOCK)  // 98
#define BN_EPS 1e-5f

typedef __attribute__((ext_vector_type(8))) short short8;   // 8 bf16 bits (4 VGPRs)
typedef __attribute__((ext_vector_type(4))) float f32x4;

__device__ inline ushort f2bf(float x) {
    union { __hip_bfloat16 h; ushort u; } cv;
    cv.h = __float2bfloat16(x);   // RNE
    return cv.u;
}

// Per 16-pair group, one wave computes contrib[16 pairs][64 cout] via 8 MFMAs
// (M16 x N64 x K64) and atomically scatters fp32 into accum.
//  A[m=lane&15][k=q*8+e]   (verified A-operand layout, q=lane>>4)
//  B[k=q*8+e][j=lane&15]   (mirror layout)
//  D: pair=q*4+reg, cout=ntile*16+(lane&15)   (verified C/D layout)
__global__ __launch_bounds__(256) void conv_scatter_kernel(
    const float* __restrict__ feats,      // fp32 [NPTS][CIN]
    const float* __restrict__ wk,         // fp32 [KVOL][CIN][COUT]
    const int* __restrict__ in_map,       // [KVOL][NPAIRS]
    const int* __restrict__ out_map,      // [KVOL][NPAIRS]
    float* __restrict__ accum)            // [NPTS][COUT] fp32
{
    const int koff  = blockIdx.x / CHUNKS_PER_K;
    const int chunk = blockIdx.x % CHUNKS_PER_K;
    const int lane  = threadIdx.x & 63;
    const int wave  = threadIdx.x >> 6;
    const int m     = lane & 15;
    const int q     = lane >> 4;

    // Load W[koff] fragments (fp32 -> bf16) once per block; amortized over 64 groups.
    short8 bfrag[2][4];
    const float* wbase = wk + koff * (CIN * COUT);
    #pragma unroll
    for (int h = 0; h < 2; ++h) {
        #pragma unroll
        for (int nt = 0; nt < 4; ++nt) {
            #pragma unroll
            for (int e = 0; e < 8; ++e) {
                const int kin = h * 32 + q * 8 + e;
                bfrag[h][nt][e] = (short)f2bf(wbase[kin * COUT + nt * 16 + m]);
            }
        }
    }

    const int* imap = in_map + koff * NPAIRS;
    const int* omap = out_map + koff * NPAIRS;

    #pragma unroll 1
    for (int it = 0; it < GROUPS_PER_BLOCK / 4; ++it) {
        const int g = chunk * GROUPS_PER_BLOCK + it * 4 + wave;
        if (g >= GROUPS_PER_K) break;
        const int base = g * 16;

        // Gather A: lane m owns row in_map[base+m]; cols q*8..q*8+7 (a0) and +32 (a1).
        const int row = imap[base + m];
        const float* fr = feats + row * CIN + q * 8;
        const f32x4 f00 = *(const f32x4*)(fr);
        const f32x4 f01 = *(const f32x4*)(fr + 4);
        const f32x4 f10 = *(const f32x4*)(fr + 32);
        const f32x4 f11 = *(const f32x4*)(fr + 36);

        short8 a0, a1;
        #pragma unroll
        for (int e = 0; e < 4; ++e) {
            a0[e]     = (short)f2bf(f00[e]);
            a0[e + 4] = (short)f2bf(f01[e]);
            a1[e]     = (short)f2bf(f10[e]);
            a1[e + 4] = (short)f2bf(f11[e]);
        }

        f32x4 acc[4];
        #pragma unroll
        for (int nt = 0; nt < 4; ++nt) acc[nt] = (f32x4){0.f, 0.f, 0.f, 0.f};
        #pragma unroll
        for (int nt = 0; nt < 4; ++nt) {
            acc[nt] = __builtin_amdgcn_mfma_f32_16x16x32_bf16(a0, bfrag[0][nt], acc[nt], 0, 0, 0);
            acc[nt] = __builtin_amdgcn_mfma_f32_16x16x32_bf16(a1, bfrag[1][nt], acc[nt], 0, 0, 0);
        }

        int orow[4];
        #pragma unroll
        for (int r = 0; r < 4; ++r) orow[r] = omap[base + q * 4 + r];

        #pragma unroll
        for (int nt = 0; nt < 4; ++nt) {
            #pragma unroll
            for (int r = 0; r < 4; ++r) {
                atomicAdd(accum + orow[r] * COUT + nt * 16 + m, acc[nt][r]);
            }
        }
    }
}

// BN (inference-folded) + ReLU; fp32 accum -> fp32 out.
__global__ __launch_bounds__(256) void bn_relu_kernel(
    const float* __restrict__ accum,
    const float* __restrict__ gamma,
    const float* __restrict__ beta,
    const float* __restrict__ rmean,
    const float* __restrict__ rvar,
    float* __restrict__ out)
{
    __shared__ float s_scale[COUT];
    __shared__ float s_bias[COUT];
    if (threadIdx.x < COUT) {
        const int c = threadIdx.x;
        const float sc = gamma[c] * rsqrtf(rvar[c] + BN_EPS);
        s_scale[c] = sc;
        s_bias[c]  = beta[c] - rmean[c] * sc;
    }
    __syncthreads();

    const int idx = (blockIdx.x * 256 + threadIdx.x) * 4;
    if (idx < NPTS * COUT) {
        const f32x4 v = *(const f32x4*)(accum + idx);
        const int c0 = idx & (COUT - 1);   // 4 | COUT, so c0..c0+3 stay in-row
        f32x4 o;
        #pragma unroll
        for (int e = 0; e < 4; ++e) {
            o[e] = fmaxf(v[e] * s_scale[c0 + e] + s_bias[c0 + e], 0.f);
        }
        *(f32x4*)(out + idx) = o;
    }
}

extern "C" void kernel_launch(void* const* d_in, const int* in_sizes, int n_in,
                              void* d_out, int out_size, void* d_ws, size_t ws_size,
                              hipStream_t stream) {
    const float* feats = (const float*)d_in[0];
    const float* wk    = (const float*)d_in[1];
    const float* gamma = (const float*)d_in[2];
    const float* beta  = (const float*)d_in[3];
    const float* rmean = (const float*)d_in[4];
    const float* rvar  = (const float*)d_in[5];
    const int* imap    = (const int*)d_in[6];
    const int* omap    = (const int*)d_in[7];
    float* out         = (float*)d_out;
    float* accum       = (float*)d_ws;   // 200000*64*4 = 51.2 MB scratch

    hipMemsetAsync(accum, 0, (size_t)NPTS * COUT * sizeof(float), stream);

    conv_scatter_kernel<<<KVOL * CHUNKS_PER_K, 256, 0, stream>>>(feats, wk, imap, omap, accum);

    bn_relu_kernel<<<(NPTS * COUT / 4 + 255) / 256, 256, 0, stream>>>(
        accum, gamma, beta, rmean, rvar, out);
}